// Round 6
// baseline (427.908 us; speedup 1.0000x reference)
//
#include <hip/hip_runtime.h>
#include <math.h>

// GRU-D, diagonal weights: independent scalar recurrence per (b,f) over T.
// R7: R1..R6 all plateau at 150-185us / ~2.0 TB/s regardless of schedule
// (barriered producer-consumer, register dbuf x3, counted-vmcnt LDS-DMA
// dbuf). Diagnosis: bytes-in-flight equilibrium. Delivered BW = in-flight /
// latency; all prior variants hold ~6-12 MB in flight device-wide (dword
// ops, <=63/wave, 1024-wave occupancy cap) -> ~2 TB/s at ~4-6us loaded
// latency. The only remaining lever is BYTES PER OP: each global_load_lds
// now moves 16B/lane = 1 KB/op (a full 256-feature row), waves cooperate
// (each wave DMAs 6 of the 24 rows per chunk), and a 5-slot LDS ring with
// depth-4 prefetch holds ~24 MB in flight device-wide (4x R6). Cross-wave
// handoff: each wave waits its OWN counted vmcnt then raw s_barrier (m201
// pattern) -- no __syncthreads, nothing ever drains vmcnt to 0.
//
// Steady phase c: [vmcnt(42)=3x8 st + 3x6 ld newer] [s_barrier]
// [compute chunk c from LDS: 8 nt-stores] [issue 6x1KB DMA for chunk c+4].
// Peak outstanding 56 <= 63. WAR on ring slot (c+4)%5==(c-1)%5 is protected
// by the barrier (all waves passed compute(c-1) before any wave issues).

#define TT 512
#define BB 256
#define FF 256
#define BF (BB * FF)        // elements per time step per array
#define CH 8                // steps per chunk
#define NCH (TT / CH)       // 64 chunks
#define NB 5                // ring slots (120 KiB LDS)

__device__ __forceinline__ float fast_sigmoid(float x) {
    return __builtin_amdgcn_rcpf(1.0f + __expf(-x));
}
__device__ __forceinline__ float fast_tanh(float x) {
    return fmaf(-2.0f, __builtin_amdgcn_rcpf(1.0f + __expf(2.0f * x)), 1.0f);
}

typedef __attribute__((address_space(1))) const void gconst_void;
typedef __attribute__((address_space(3))) void lds_void;

// HBM -> LDS DMA, 16B per lane: lane i's 16B from its own global address
// lands at ldsbase + 16*i. 1 KB per instruction, no VGPR destination.
__device__ __forceinline__ void gload_lds16(const float* g, float* l) {
    __builtin_amdgcn_global_load_lds((gconst_void*)g, (lds_void*)l, 16, 0, 0);
}

// Counted wait + scheduler fence (fence mandatory per rule #18).
#define VMWAIT(N)                                                   \
    do {                                                            \
        asm volatile("s_waitcnt vmcnt(" #N ")" ::: "memory");       \
        __builtin_amdgcn_sched_barrier(0);                          \
    } while (0)

// Raw workgroup barrier WITHOUT the __syncthreads vmcnt(0) drain.
#define SBAR()                                                      \
    do {                                                            \
        __builtin_amdgcn_s_barrier();                               \
        __builtin_amdgcn_sched_barrier(0);                          \
    } while (0)

__global__ __launch_bounds__(256, 1) void grud_kernel(
    const float* __restrict__ X, const float* __restrict__ Mask,
    const float* __restrict__ Delta,
    const float* __restrict__ x_mean,
    const float* __restrict__ w_dg_x, const float* __restrict__ b_dg_x,
    const float* __restrict__ w_dg_h, const float* __restrict__ b_dg_h,
    const float* __restrict__ w_xz, const float* __restrict__ u_hz,
    const float* __restrict__ b_z,
    const float* __restrict__ w_xr, const float* __restrict__ u_hr,
    const float* __restrict__ b_r,
    const float* __restrict__ w_xh, const float* __restrict__ u_hh,
    const float* __restrict__ v_mh, const float* __restrict__ b_h,
    float* __restrict__ out)
{
    // ring: [slot][arr][step][feature] : 5*3*8*256*4B = 120 KiB
    __shared__ float lds[NB][3][CH][FF];

    const int tid = threadIdx.x;        // 0..255 : feature index f
    const int w   = tid >> 6;           // wave id 0..3
    const int ln  = tid & 63;           // lane id
    const int b   = blockIdx.x;         // batch index

    // per-lane DMA source base: features 4*ln..4*ln+3 of batch b (16B aligned)
    const size_t rb = (size_t)b * FF + 4 * (size_t)ln;
    const float* __restrict__ gx = X     + rb;
    const float* __restrict__ gm = Mask  + rb;
    const float* __restrict__ gd = Delta + rb;

    float* __restrict__ ob = out + (size_t)b * TT * FF + tid;

    // per-feature parameters (coalesced, loaded once)
    const float xm  = x_mean[tid];
    const float wdx = w_dg_x[tid], bdx = b_dg_x[tid];
    const float wdh = w_dg_h[tid], bdh = b_dg_h[tid];
    const float wxz = w_xz[tid],   uhz = u_hz[tid], bz = b_z[tid];
    const float wxr = w_xr[tid],   uhr = u_hr[tid], br = b_r[tid];
    const float wxh = w_xh[tid],   uhh = u_hh[tid];
    const float vmh = v_mh[tid],   bh  = b_h[tid];

    // Resolve the tracked param-load waits here, before any untracked DMA,
    // so no compiler waitcnt lands inside the pipeline.
    asm volatile("" :: "v"(xm), "v"(wdx), "v"(bdx), "v"(wdh), "v"(bdh),
                       "v"(wxz), "v"(uhz), "v"(bz), "v"(wxr), "v"(uhr),
                       "v"(br), "v"(wxh), "v"(uhh), "v"(vmh), "v"(bh));
    float h = 0.0f;

    // issue one chunk: this wave DMAs rows (arr=0..2, s=2w..2w+1) = 6 KB
    auto issuec = [&](int c, int slot) {
        const size_t t0 = (size_t)c * CH;
        #pragma unroll
        for (int j = 0; j < 2; ++j) {
            const int s = 2 * w + j;                   // wave-uniform
            const size_t off = (t0 + (size_t)s) * BF;  // element offset
            gload_lds16(gx + off, &lds[slot][0][s][0]);
            gload_lds16(gm + off, &lds[slot][1][s][0]);
            gload_lds16(gd + off, &lds[slot][2][s][0]);
        }
        __builtin_amdgcn_sched_barrier(0);
    };

    // compute one chunk from LDS (ds_read_b32, lane-linear: conflict-free)
    auto computec = [&](int c, int slot) {
        float* op = ob + (size_t)c * CH * FF;
        #pragma unroll
        for (int s = 0; s < CH; ++s) {
            float x = lds[slot][0][s][tid];
            float m = lds[slot][1][s][tid];
            float d = lds[slot][2][s][tid];
            float gxx = __expf(-fmaxf(0.0f, fmaf(wdx, d, bdx)));
            float ghh = __expf(-fmaxf(0.0f, fmaf(wdh, d, bdh)));
            float xhat = fmaf(gxx, x, (1.0f - gxx) * xm);
            x = fmaf(m, x, (1.0f - m) * xhat);
            h = ghh * h;
            float z  = fast_sigmoid(fmaf(wxz, x, fmaf(uhz, h, bz)));
            float r  = fast_sigmoid(fmaf(wxr, x, fmaf(uhr, h, br)));
            float ht = fast_tanh(fmaf(wxh, x, fmaf(uhh, r * h, fmaf(vmh, m, bh))));
            h = fmaf(z, ht - h, h);               // (1-z)*h + z*ht
            __builtin_nontemporal_store(h, op + (size_t)s * FF);
        }
        __builtin_amdgcn_sched_barrier(0);
    };

    // ---- prologue: 4 chunks (24 DMA ops/wave, 96 KB/block) in flight ----
    issuec(0, 0); issuec(1, 1); issuec(2, 2); issuec(3, 3);

    // phase 0: newer than ld(0) = ld(1,2,3) = 18
    VMWAIT(18); SBAR(); computec(0, 0); issuec(4, 4);
    // phase 1: newer than ld(1) = ld(2)6+ld(3)6+st(0)8+ld(4)6 = 26
    VMWAIT(26); SBAR(); computec(1, 1); issuec(5, 0);
    // phase 2: newer than ld(2) = ld(3)6+st(0)8+ld(4)6+st(1)8+ld(5)6 = 34
    VMWAIT(34); SBAR(); computec(2, 2); issuec(6, 1);

    // ---- steady state: phases 3..59, newer = 3x8 st + 3x6 ld = 42 ----
    int cs = 3, is_ = 2;
    for (int c = 3; c <= NCH - 5; ++c) {          // c = 3..59
        VMWAIT(42); SBAR();
        computec(c, cs);
        issuec(c + 4, is_);                       // chunks 7..63
        cs  = (cs  + 1 == NB) ? 0 : cs  + 1;
        is_ = (is_ + 1 == NB) ? 0 : is_ + 1;
    }

    // ---- tail: chunks 60..63 (slots 0..3), no further issues ----
    VMWAIT(42); SBAR(); computec(60, 0);   // newer: st(57,58,59)+ld(61,62,63)
    VMWAIT(36); SBAR(); computec(61, 1);   // newer: st(58,59,60)+ld(62,63)
    VMWAIT(30); SBAR(); computec(62, 2);   // newer: st(59,60,61)+ld(63)
    VMWAIT(24); SBAR(); computec(63, 3);   // newer: st(60,61,62)

    // second output: last hidden state [B, H]
    out[(size_t)BB * TT * FF + (size_t)b * FF + tid] = h;
}

extern "C" void kernel_launch(void* const* d_in, const int* in_sizes, int n_in,
                              void* d_out, int out_size, void* d_ws, size_t ws_size,
                              hipStream_t stream) {
    const float* X      = (const float*)d_in[0];
    const float* Mask   = (const float*)d_in[1];
    const float* Delta  = (const float*)d_in[2];
    const float* x_mean = (const float*)d_in[3];
    const float* w_dg_x = (const float*)d_in[4];
    const float* b_dg_x = (const float*)d_in[5];
    const float* w_dg_h = (const float*)d_in[6];
    const float* b_dg_h = (const float*)d_in[7];
    const float* w_xz   = (const float*)d_in[8];
    const float* u_hz   = (const float*)d_in[9];
    const float* b_z    = (const float*)d_in[10];
    const float* w_xr   = (const float*)d_in[11];
    const float* u_hr   = (const float*)d_in[12];
    const float* b_r    = (const float*)d_in[13];
    const float* w_xh   = (const float*)d_in[14];
    const float* u_hh   = (const float*)d_in[15];
    const float* v_mh   = (const float*)d_in[16];
    const float* b_h    = (const float*)d_in[17];
    float* out = (float*)d_out;

    grud_kernel<<<BB, 256, 0, stream>>>(
        X, Mask, Delta, x_mean, w_dg_x, b_dg_x, w_dg_h, b_dg_h,
        w_xz, u_hz, b_z, w_xr, u_hr, b_r, w_xh, u_hh, v_mh, b_h, out);
}